// Round 3
// baseline (1625.405 us; speedup 1.0000x reference)
//
#include <hip/hip_runtime.h>
#include <math.h>

#define NPIX 16384
#define EPSF 1e-8f

__device__ __forceinline__ float wred64(float s){
  s += __shfl_xor(s, 32); s += __shfl_xor(s, 16); s += __shfl_xor(s, 8);
  s += __shfl_xor(s, 4);  s += __shfl_xor(s, 2);  s += __shfl_xor(s, 1);
  return s;
}
__device__ __forceinline__ float rdlane(float v, int l){
  return __int_as_float(__builtin_amdgcn_readlane(__float_as_int(v), l));
}
__device__ __forceinline__ float dot4f(float4 a, float4 b, float acc){
  acc = fmaf(a.x,b.x,acc); acc = fmaf(a.y,b.y,acc);
  acc = fmaf(a.z,b.z,acc); acc = fmaf(a.w,b.w,acc);
  return acc;
}

// ---------------- prep: zero the BN-stats accumulators (graph-replay safe) ----------------
__global__ __launch_bounds__(256) void prep_kernel(float* __restrict__ stats){
  int gid = blockIdx.x*256 + threadIdx.x;
  if (gid < 512) stats[gid] = 0.f;
}

// ---------------- conv1: 3x3, Cin=3 -> 64, planar output. wave = 64px x 16 cout ----------------
__global__ __launch_bounds__(256) void conv1p_kernel(const float* __restrict__ x, const float* __restrict__ w,
                                                     const float* __restrict__ bias, float* __restrict__ out){
  int blk = blockIdx.x;                 // 512 = b(2) * y(128) * xh(2)
  int xh = blk & 1; int y = (blk>>1) & 127; int b = blk >> 8;
  int x0 = xh << 6;
  int lane = threadIdx.x & 63, wid = threadIdx.x >> 6;
  int cg = __builtin_amdgcn_readfirstlane(wid);       // 16-cout group
  // 27 per-lane inputs (zero-padded at borders)
  float iv[9][3];
  #pragma unroll
  for (int ky=0; ky<3; ++ky){
    int ny = y + ky - 1;
    #pragma unroll
    for (int kx=0; kx<3; ++kx){
      int nx = x0 + lane + kx - 1;
      bool ok = ((unsigned)ny < 128u) && ((unsigned)nx < 128u);
      const float* ip = x + (((b<<14) + ny*128 + nx))*3;
      #pragma unroll
      for (int ci=0; ci<3; ++ci) iv[ky*3+kx][ci] = ok ? ip[ci] : 0.f;
    }
  }
  float acc[16];
  {
    const float* bp = bias + cg*16;
    #pragma unroll
    for (int j=0;j<16;++j) acc[j] = bp[j];
  }
  #pragma unroll
  for (int t=0; t<9; ++t){
    #pragma unroll
    for (int ci=0; ci<3; ++ci){
      const float* wp = w + (t*3+ci)*64 + cg*16;      // wave-uniform -> s_load
      float v = iv[t][ci];
      #pragma unroll
      for (int j=0;j<16;++j) acc[j] = fmaf(v, wp[j], acc[j]);
    }
  }
  float* op = out + ((b<<6) + cg*16)*NPIX + y*128 + x0 + lane;
  #pragma unroll
  for (int j=0;j<16;++j) op[j*NPIX] = fmaxf(acc[j], 0.f);
}

// ---------------- conv3x3 64->64 planar; LDS-staged input (optional fused BN+ReLU on input),
// optional bias, optional output relu, optional fused output stats ----------------
__global__ __launch_bounds__(256) void conv3p_kernel(
    const float* __restrict__ in, const float* __restrict__ w, const float* __restrict__ bias,
    const float* __restrict__ bnst, const float* __restrict__ bng, const float* __restrict__ bnb,
    float* __restrict__ out, float* __restrict__ ost, int relu)
{
  __shared__ float lin[3*64*66];        // [ky][ci][66] (x0-1 .. x0+64)
  int blk = blockIdx.x;                 // 1024 = b(2) * y(128) * xh(2) * cb(2)
  int cb = blk & 1; int xh = (blk>>1) & 1; int y = (blk>>2) & 127; int b = blk >> 9;
  int x0 = xh << 6;
  int tid = threadIdx.x;
  for (int s = tid; s < 3*64*66; s += 256){
    int row = s / 66; int xx = s - row*66;
    int ky = row >> 6; int ci = row & 63;
    int ny = y + ky - 1;
    int gx = x0 - 1 + xx;
    float v = 0.f;
    if ((unsigned)ny < 128u && (unsigned)gx < 128u){
      v = in[((b<<6)+ci)*NPIX + ny*128 + gx];
      if (bnst){
        float mu  = bnst[ci]    * (1.f/32768.f);
        float var = bnst[64+ci] * (1.f/32768.f) - mu*mu;
        float a = bng[ci] * rsqrtf(var + 1e-5f);
        v = fmaxf(fmaf(v, a, bnb[ci] - mu*a), 0.f);
      }
    }
    lin[s] = v;
  }
  __syncthreads();
  int wid = tid >> 6, lane = tid & 63;
  int g = __builtin_amdgcn_readfirstlane(cb*4 + wid); // cout group 0..7
  int c0 = g << 3;
  float acc[8];
  if (bias){
    const float* bp = bias + c0;
    #pragma unroll
    for (int j=0;j<8;++j) acc[j] = bp[j];
  } else {
    #pragma unroll
    for (int j=0;j<8;++j) acc[j] = 0.f;
  }
  #pragma unroll 1
  for (int ky=0; ky<3; ++ky){
    const float* lrow = lin + ky*64*66 + lane;
    const float* wrow = w + (ky*3)*4096 + c0;
    #pragma unroll 2
    for (int ci=0; ci<64; ++ci){
      const float* lp = lrow + ci*66;
      float v0 = lp[0], v1 = lp[1], v2 = lp[2];
      const float* wp0 = wrow + ci*64;                // kx=0  (wave-uniform -> s_loadx8)
      const float* wp1 = wp0 + 4096;                  // kx=1
      const float* wp2 = wp0 + 8192;                  // kx=2
      #pragma unroll
      for (int j=0;j<8;++j){
        acc[j] = fmaf(v0, wp0[j], acc[j]);
        acc[j] = fmaf(v1, wp1[j], acc[j]);
        acc[j] = fmaf(v2, wp2[j], acc[j]);
      }
    }
  }
  float* op = out + ((b<<6)+c0)*NPIX + y*128 + x0 + lane;
  #pragma unroll
  for (int j=0;j<8;++j){
    float vv = acc[j];
    if (relu) vv = fmaxf(vv, 0.f);
    op[j*NPIX] = vv;
  }
  if (ost){
    #pragma unroll
    for (int j=0;j<8;++j){
      float s1 = wred64(acc[j]);
      float s2 = wred64(acc[j]*acc[j]);
      if (lane == 0){ atomicAdd(&ost[c0+j], s1); atomicAdd(&ost[64+c0+j], s2); }
    }
  }
}

// ---------------- t = relu(f + a*t + b) planar, in place ----------------
__global__ __launch_bounds__(256) void resfusep_kernel(float* __restrict__ t, const float* __restrict__ f,
                                                       const float* __restrict__ stats, const float* __restrict__ g,
                                                       const float* __restrict__ beta){
  int idx4 = blockIdx.x*256 + threadIdx.x;            // 524288 float4s
  int ci = (idx4 >> 12) & 63;
  float mu  = stats[ci]    * (1.f/32768.f);
  float var = stats[64+ci] * (1.f/32768.f) - mu*mu;
  float a  = g[ci] * rsqrtf(var + 1e-5f);
  float bb = beta[ci] - mu*a;
  float4 v = ((float4*)t)[idx4];
  float4 fv = ((const float4*)f)[idx4];
  v.x = fmaxf(fv.x + fmaf(v.x, a, bb), 0.f);
  v.y = fmaxf(fv.y + fmaf(v.y, a, bb), 0.f);
  v.z = fmaxf(fv.z + fmaf(v.z, a, bb), 0.f);
  v.w = fmaxf(fv.w + fmaf(v.w, a, bb), 0.f);
  ((float4*)t)[idx4] = v;
}

// ---------------- 1x1 projection: planar in -> pixel-major out + per-pixel norm ----------------
__global__ __launch_bounds__(256) void projp_kernel(const float* __restrict__ r, const float* __restrict__ w,
                                                    const float* __restrict__ bias, float* __restrict__ outp,
                                                    float* __restrict__ nrm){
  __shared__ float tin[64*66];          // [ci][px] pad 66
  __shared__ float t2[64*69];           // [px][cout] pad 69
  __shared__ float nsum[4*64];
  int blk = blockIdx.x;                 // 512 = b(2) * tile(256)
  int b = blk >> 8; int p0 = (blk & 255) << 6;
  int tid = threadIdx.x;
  for (int s = tid; s < 4096; s += 256){
    int ci = s >> 6, xx = s & 63;
    tin[ci*66 + xx] = r[((b<<6)+ci)*NPIX + p0 + xx];
  }
  __syncthreads();
  int lane = tid & 63, wid = tid >> 6;
  int cg = __builtin_amdgcn_readfirstlane(wid);       // 16-cout chunk
  float acc[16];
  if (bias){
    const float* bp = bias + cg*16;
    #pragma unroll
    for (int j=0;j<16;++j) acc[j] = bp[j];
  } else {
    #pragma unroll
    for (int j=0;j<16;++j) acc[j] = 0.f;
  }
  #pragma unroll 2
  for (int ci=0; ci<64; ++ci){
    float v = tin[ci*66 + lane];
    const float* wp = w + ci*64 + cg*16;              // wave-uniform -> s_loadx16
    #pragma unroll
    for (int j=0;j<16;++j) acc[j] = fmaf(v, wp[j], acc[j]);
  }
  float ss = 0.f;
  #pragma unroll
  for (int j=0;j<16;++j) ss += acc[j]*acc[j];
  nsum[wid*64 + lane] = ss;
  #pragma unroll
  for (int j=0;j<16;++j) t2[lane*69 + cg*16 + j] = acc[j];
  __syncthreads();
  if (wid == 0){
    float tot = nsum[lane] + nsum[64+lane] + nsum[128+lane] + nsum[192+lane];
    nrm[(b<<14) + p0 + lane] = sqrtf(tot);
  }
  for (int s = tid; s < 4096; s += 256){
    int px = s >> 6, c = s & 63;
    outp[((b<<14) + p0 + px)*64 + c] = t2[px*69 + c];
  }
}

// ---------------- edge weights: W[b,i,o] = cos-sim(q_i, k_j) for 5x5 offsets ----------------
#define EW_PAD 68
__global__ __launch_bounds__(256) void edge_kernel(const float* __restrict__ qs, const float* __restrict__ ks,
                                                   const float* __restrict__ nq, const float* __restrict__ nk,
                                                   float* __restrict__ W){
  __shared__ float klds[100*EW_PAD];
  __shared__ float qlds[16*EW_PAD];
  int blk = blockIdx.x;              // 2048 = 2 batches * 128 rows * 8
  int b = blk >> 10; int rem = blk & 1023;
  int y = rem >> 3; int x0 = (rem & 7) << 4;
  int tid = threadIdx.x;
  for (int s = tid; s < 1600; s += 256){
    int cin4 = s & 15; int col = (s >> 4) % 20; int r = (s >> 4) / 20;
    int ry = y - 2 + r; ry = ry < 0 ? 0 : (ry > 127 ? 127 : ry);
    int cx = x0 - 2 + col; cx = cx < 0 ? 0 : (cx > 127 ? 127 : cx);
    float4 v = *(const float4*)(ks + (((b<<14) + ry*128 + cx)<<6) + cin4*4);
    *(float4*)(klds + (r*20+col)*EW_PAD + cin4*4) = v;
  }
  {
    int cin4 = tid & 15; int px = tid >> 4;
    float4 v = *(const float4*)(qs + (((b<<14) + y*128 + x0 + px)<<6) + cin4*4);
    *(float4*)(qlds + px*EW_PAD + cin4*4) = v;
  }
  __syncthreads();
  #pragma unroll
  for (int pair=0; pair<2; ++pair){
    int t2 = tid + pair*256;
    int px = t2 >> 5; int o = t2 & 31;
    if (o < 25){
      int dy = o/5 - 2, dx = o%5 - 2;
      int yy = y + dy, xx = x0 + px + dx;
      bool valid = ((unsigned)yy < 128u) && ((unsigned)xx < 128u);
      const float* kq = klds + ((dy+2)*20 + (px+dx+2))*EW_PAD;
      const float* qq = qlds + px*EW_PAD;
      float a0 = 0.f, a1 = 0.f;
      #pragma unroll
      for (int q=0; q<16; q+=2){
        a0 = dot4f(*(const float4*)(qq + q*4),     *(const float4*)(kq + q*4),     a0);
        a1 = dot4f(*(const float4*)(qq + (q+1)*4), *(const float4*)(kq + (q+1)*4), a1);
      }
      float acc = a0 + a1;
      int gp = (b<<14) + y*128 + x0 + px;
      float wv_ = 0.f;
      if (valid){
        int gj = (b<<14) + yy*128 + xx;
        float rq = 1.f / fmaxf(nq[gp], EPSF);
        float rk = 1.f / fmaxf(nk[gj], EPSF);
        wv_ = acc * rq * rk;
      }
      W[gp*25 + o] = wv_;
    }
  }
}

// ---------------- one message-passing iteration (register sliding window) ----------------
__global__ __launch_bounds__(256) void mp_iter_kernel(const float* __restrict__ src, float* __restrict__ dst,
                                                      const float* __restrict__ W){
  int lane = threadIdx.x & 63;
  int wid  = threadIdx.x >> 6;
  int blk  = blockIdx.x;               // 1024
  int xcd = blk & 7, s = blk >> 3;     // XCD-contiguous rows for L2 locality
  int row_id = xcd*32 + (s >> 2);      // 0..255 (2 batches x 128 rows)
  int q4 = s & 3;
  int b = row_id >> 7, y = row_id & 127;
  int x0 = ((q4 << 2) + wid) << 3;     // 8-pixel group start col
  int gp0 = (b << 14) + y*128 + x0;
  int lo = lane < 25 ? lane : 24;
  float wv[8];
  #pragma unroll
  for (int p=0;p<8;++p) wv[p] = W[(gp0+p)*25 + lo];
  const float* rp[5];
  #pragma unroll
  for (int r=0;r<5;++r){
    int ry = y - 2 + r; ry = ry < 0 ? 0 : (ry > 127 ? 127 : ry);
    rp[r] = src + (((b<<14) + ry*128) << 7) + lane;
  }
  float wa[5][5], wb[5][5];
  #pragma unroll
  for (int cc=0; cc<4; ++cc){
    int xc = x0 - 2 + cc; if (xc < 0) xc = 0;
    int off = xc << 7;
    #pragma unroll
    for (int r=0;r<5;++r){ wa[r][cc] = rp[r][off]; wb[r][cc] = rp[r][off + 64]; }
  }
  #pragma unroll
  for (int p=0;p<8;++p){
    int xl = x0 + p + 2; if (xl > 127) xl = 127;
    int off = xl << 7;
    #pragma unroll
    for (int r=0;r<5;++r){ wa[r][4] = rp[r][off]; wb[r][4] = rp[r][off + 64]; }
    float a0 = 0.f, a1 = 0.f;
    #pragma unroll
    for (int r=0;r<5;++r){
      #pragma unroll
      for (int cc=0;cc<5;++cc){
        float w = rdlane(wv[p], r*5+cc);
        a0 = fmaf(w, wa[r][cc], a0);
        a1 = fmaf(w, wb[r][cc], a1);
      }
    }
    float ss = wred64(a0*a0 + a1*a1);
    float sc = 1.f / fmaxf(sqrtf(ss), EPSF);
    float* dp = dst + ((gp0 + p) << 7) + lane;
    dp[0] = a0*sc; dp[64] = a1*sc;
    #pragma unroll
    for (int r=0;r<5;++r){
      #pragma unroll
      for (int cc=0;cc<4;++cc){ wa[r][cc] = wa[r][cc+1]; wb[r][cc] = wb[r][cc+1]; }
    }
  }
}

// ---------------- normalize agent pixels ----------------
__global__ void mp_agents_kernel(const float* __restrict__ hf, const int* __restrict__ agidx,
                                 float* __restrict__ agbuf){
  int lane = threadIdx.x & 63; int w = threadIdx.x >> 6;  // 16 waves
  int ab = w >> 3, m = w & 7;
  int ai = agidx[m];
  const float* hp = hf + (((ab<<14) + ai) << 7) + lane;
  float v0 = hp[0], v1 = hp[64];
  float ss = wred64(v0*v0 + v1*v1);
  float sc = 1.f / fmaxf(sqrtf(ss), EPSF);
  float* ap = agbuf + (((ab<<3) + m) << 7) + lane;
  ap[0] = v0*sc; ap[64] = v1*sc;
}

// ---------------- final: pix-norm, sim vs agents, softmax, transposed write ----------------
__global__ __launch_bounds__(256) void mp_final_kernel(const float* __restrict__ hf, const float* __restrict__ agbuf,
                                                       float* __restrict__ out){
  int lane = threadIdx.x & 63;
  int wid  = threadIdx.x >> 6;
  int blk  = blockIdx.x;
  int xcd = blk & 7, s = blk >> 3;
  int row_id = xcd*32 + (s >> 2);
  int q4 = s & 3;
  int b = row_id >> 7, y = row_id & 127;
  int x0 = ((q4 << 2) + wid) << 3;
  int gp0 = (b << 14) + y*128 + x0;
  #pragma unroll 1
  for (int p=0;p<8;++p){
    int gp = gp0 + p;
    const float* hp = hf + (gp << 7) + lane;
    float v0 = hp[0], v1 = hp[64];
    float ss = wred64(v0*v0 + v1*v1);
    float sc = 1.f / fmaxf(sqrtf(ss), EPSF);
    float p0 = v0*sc, p1 = v1*sc;
    float sim[8];
    #pragma unroll
    for (int m=0;m<8;++m){
      const float* ap = agbuf + (((b<<3) + m) << 7) + lane;
      sim[m] = wred64(p0*ap[0] + p1*ap[64]);
    }
    float mx = sim[0];
    #pragma unroll
    for (int m=1;m<8;++m) mx = fmaxf(mx, sim[m]);
    float e[8]; float sum = 0.f;
    #pragma unroll
    for (int m=0;m<8;++m){ e[m] = __expf((sim[m]-mx)*10.f); sum += e[m]; }
    float rs = 1.f / sum;
    if (lane < 8){
      float val = e[0];
      #pragma unroll
      for (int m=1;m<8;++m) val = (lane==m) ? e[m] : val;
      out[(((b<<3)+lane)<<14) + y*128 + x0 + p] = val * rs;
    }
  }
}

extern "C" void kernel_launch(void* const* d_in, const int* in_sizes, int n_in,
                              void* d_out, int out_size, void* d_ws, size_t ws_size,
                              hipStream_t stream) {
  (void)in_sizes; (void)n_in; (void)out_size; (void)ws_size;
  const float* x     = (const float*)d_in[0];
  const float* w_bb1 = (const float*)d_in[1];
  const float* b_bb1 = (const float*)d_in[2];
  const float* w_bb2 = (const float*)d_in[3];
  const float* b_bb2 = (const float*)d_in[4];
  const float* w_k1  = (const float*)d_in[5];
  const float* g_k1  = (const float*)d_in[6];
  const float* t_k1  = (const float*)d_in[7];
  const float* w_k2  = (const float*)d_in[8];
  const float* g_k2  = (const float*)d_in[9];
  const float* t_k2  = (const float*)d_in[10];
  const float* w_kp  = (const float*)d_in[11];
  const float* b_kp  = (const float*)d_in[12];
  const float* w_q1  = (const float*)d_in[13];
  const float* g_q1  = (const float*)d_in[14];
  const float* t_q1  = (const float*)d_in[15];
  const float* w_q2  = (const float*)d_in[16];
  const float* g_q2  = (const float*)d_in[17];
  const float* t_q2  = (const float*)d_in[18];
  const float* w_qp  = (const float*)d_in[19];
  const float* h0    = (const float*)d_in[20];
  const int*   agidx = (const int*)d_in[23];
  float* out = (float*)d_out;
  float* ws  = (float*)d_ws;

  // workspace layout (floats); hA/hB alias conv buffers (dead by MP time)
  float* F1 = ws + 0;          // planar [2][64][16384]
  float* F  = ws + 2097152;    // planar
  float* T1 = ws + 4194304;    // planar
  float* T2 = ws + 6291456;    // planar
  float* KS = ws + 8388608;    // pixel-major [2][16384][64]
  float* QS = ws + 10485760;   // pixel-major
  float* WW = ws + 12582912;   // 819200
  float* NK = ws + 13402112;   // 32768
  float* NQ = ws + 13434880;   // 32768
  float* ST = ws + 13467648;   // 512  (k1:0, k2:128, q1:256, q2:384)
  float* AG = ws + 13468160;   // 2048
  float* HA = ws + 0;          // 4194304 (aliases F1,F)
  float* HB = ws + 4194304;    // 4194304 (aliases T1,T2)

  prep_kernel<<<2, 256, 0, stream>>>(ST);
  conv1p_kernel<<<512, 256, 0, stream>>>(x, w_bb1, b_bb1, F1);
  conv3p_kernel<<<1024, 256, 0, stream>>>(F1, w_bb2, b_bb2, nullptr, nullptr, nullptr, F, nullptr, 1);
  // K branch
  conv3p_kernel<<<1024, 256, 0, stream>>>(F, w_k1, nullptr, nullptr, nullptr, nullptr, T1, ST + 0, 0);
  conv3p_kernel<<<1024, 256, 0, stream>>>(T1, w_k2, nullptr, ST + 0, g_k1, t_k1, T2, ST + 128, 0);
  resfusep_kernel<<<2048, 256, 0, stream>>>(T2, F, ST + 128, g_k2, t_k2);
  projp_kernel<<<512, 256, 0, stream>>>(T2, w_kp, b_kp, KS, NK);
  // Q branch
  conv3p_kernel<<<1024, 256, 0, stream>>>(F, w_q1, nullptr, nullptr, nullptr, nullptr, T1, ST + 256, 0);
  conv3p_kernel<<<1024, 256, 0, stream>>>(T1, w_q2, nullptr, ST + 256, g_q1, t_q1, T2, ST + 384, 0);
  resfusep_kernel<<<2048, 256, 0, stream>>>(T2, F, ST + 384, g_q2, t_q2);
  projp_kernel<<<512, 256, 0, stream>>>(T2, w_qp, nullptr, QS, NQ);
  // edge weights
  edge_kernel<<<2048, 256, 0, stream>>>(QS, KS, NQ, NK, WW);
  // 32 message-passing iterations (ping-pong)
  const float* sbuf = h0;
  for (int it = 0; it < 32; ++it){
    float* dbuf = (it & 1) ? HB : HA;
    mp_iter_kernel<<<1024, 256, 0, stream>>>(sbuf, dbuf, WW);
    sbuf = dbuf;
  }
  mp_agents_kernel<<<1, 1024, 0, stream>>>(HB, agidx, AG);
  mp_final_kernel<<<1024, 256, 0, stream>>>(HB, AG, out);
}

// Round 4
// 901.218 us; speedup vs baseline: 1.8036x; 1.8036x over previous
//
#include <hip/hip_runtime.h>
#include <math.h>

#define NPIX 16384
#define EPSF 1e-8f

__device__ __forceinline__ float wred64(float s){
  s += __shfl_xor(s, 32); s += __shfl_xor(s, 16); s += __shfl_xor(s, 8);
  s += __shfl_xor(s, 4);  s += __shfl_xor(s, 2);  s += __shfl_xor(s, 1);
  return s;
}
__device__ __forceinline__ float rdlane(float v, int l){
  return __int_as_float(__builtin_amdgcn_readlane(__float_as_int(v), l));
}
__device__ __forceinline__ float dot4f(float4 a, float4 b, float acc){
  acc = fmaf(a.x,b.x,acc); acc = fmaf(a.y,b.y,acc);
  acc = fmaf(a.z,b.z,acc); acc = fmaf(a.w,b.w,acc);
  return acc;
}

// ---------------- prep: transpose conv weights to [tap][cin4][cout][4], zero stats ----------------
__global__ __launch_bounds__(256) void prep_kernel(const float* __restrict__ w_bb2, const float* __restrict__ w_k1,
                            const float* __restrict__ w_k2, const float* __restrict__ w_q1,
                            const float* __restrict__ w_q2, const float* __restrict__ w_kp,
                            const float* __restrict__ w_qp, float* __restrict__ wt, float* __restrict__ stats){
  int gid = blockIdx.x*256 + threadIdx.x;
  if (gid < 184320){
    int conv = gid / 36864; int d = gid % 36864;
    const float* src = conv==0? w_bb2 : conv==1? w_k1 : conv==2? w_k2 : conv==3? w_q1 : w_q2;
    int k = d & 3, cout = (d>>2) & 63, cin4 = (d>>8) & 15, tap = d >> 12;
    wt[conv*36864 + d] = src[(tap*64 + cin4*4 + k)*64 + cout];
  } else if (gid < 192512){
    int t = gid - 184320; int which = t >> 12; int d = t & 4095;
    const float* src = which ? w_qp : w_kp;
    int k = d & 3, cout = (d>>2) & 63, cin4 = d >> 8;
    wt[184320 + t] = src[(cin4*4 + k)*64 + cout];
  } else if (gid < 193024){
    stats[gid - 192512] = 0.f;
  }
}

// ---------------- conv1: 3x3, Cin=3 -> 64 (wave = 8 px x 64 cout, scalar input loads) ----------------
__global__ __launch_bounds__(256) void conv1_kernel(const float* __restrict__ x, const float* __restrict__ w,
                                                    const float* __restrict__ bias, float* __restrict__ out){
  int wv = blockIdx.x*4 + (threadIdx.x >> 6);
  int c  = threadIdx.x & 63;
  int p0 = wv << 3;
  int ub = __builtin_amdgcn_readfirstlane(p0);
  int b  = ub >> 14; int i0 = ub & (NPIX-1);
  int y  = i0 >> 7, x0 = i0 & 127;
  float wv_[9][3];
  #pragma unroll
  for (int t=0;t<9;++t)
    #pragma unroll
    for (int ci=0;ci<3;++ci) wv_[t][ci] = w[(t*3+ci)*64 + c];
  float bv = bias[c];
  float acc[8];
  #pragma unroll
  for (int p=0;p<8;++p) acc[p] = bv;
  for (int ky=0; ky<3; ++ky){
    int ny = y + ky - 1;
    if ((unsigned)ny >= 128u) continue;
    const float* rowp = x + ((b<<14) + ny*128)*3;
    for (int kx=0; kx<3; ++kx){
      int t = ky*3 + kx;
      #pragma unroll
      for (int p=0;p<8;++p){
        int col = x0 + p + kx - 1;
        if ((unsigned)col < 128u){
          const float* ip = rowp + col*3;
          acc[p] = fmaf(ip[0], wv_[t][0], acc[p]);
          acc[p] = fmaf(ip[1], wv_[t][1], acc[p]);
          acc[p] = fmaf(ip[2], wv_[t][2], acc[p]);
        }
      }
    }
  }
  float* op = out + (p0 << 6) + c;
  #pragma unroll
  for (int p=0;p<8;++p) op[p*64] = fmaxf(acc[p], 0.f);
}

// ---------------- conv3x3 64->64 (wave = 8 px x 64 cout; VGPR weights, scalar input loads) ----------------
__global__ __launch_bounds__(256) void conv3s_kernel(const float* __restrict__ in, const float* __restrict__ wt,
                                                     const float* __restrict__ bias, float* __restrict__ out, int relu){
  int wv = blockIdx.x*4 + (threadIdx.x >> 6);
  int c  = threadIdx.x & 63;
  int p0 = wv << 3;
  int ub = __builtin_amdgcn_readfirstlane(p0);
  int b  = ub >> 14; int i0 = ub & (NPIX-1);
  int y  = i0 >> 7, x0 = i0 & 127;
  float bv = bias ? bias[c] : 0.f;
  float acc[8];
  #pragma unroll
  for (int p=0;p<8;++p) acc[p] = bv;
  bool interior = (x0 > 0) && (x0 < 120);
  for (int ky=0; ky<3; ++ky){
    int ny = y + ky - 1;
    if ((unsigned)ny >= 128u) continue;
    const float* rowp = in + (((b<<14) + ny*128) << 6);
    for (int kx=0; kx<3; ++kx){
      const float4* wq = (const float4*)wt + (ky*3+kx)*1024 + c;
      #pragma unroll 1
      for (int h=0; h<2; ++h){
        float4 w[8];
        #pragma unroll
        for (int q=0;q<8;++q) w[q] = wq[(h*8+q)*64];
        if (interior){
          #pragma unroll
          for (int p=0;p<8;++p){
            const float* ip = rowp + ((x0+p+kx-1)<<6) + h*32;   // wave-uniform -> s_load
            #pragma unroll
            for (int q=0;q<8;++q)
              acc[p] = dot4f(*(const float4*)(ip + (q<<2)), w[q], acc[p]);
          }
        } else {
          #pragma unroll
          for (int p=0;p<8;++p){
            int col = x0 + p + kx - 1;
            if ((unsigned)col < 128u){
              const float* ip = rowp + (col<<6) + h*32;
              #pragma unroll
              for (int q=0;q<8;++q)
                acc[p] = dot4f(*(const float4*)(ip + (q<<2)), w[q], acc[p]);
            }
          }
        }
      }
    }
  }
  float* op = out + (p0 << 6) + c;
  #pragma unroll
  for (int p=0;p<8;++p){
    float v = acc[p];
    if (relu) v = fmaxf(v, 0.f);
    op[p*64] = v;
  }
}

// ---------------- dual conv3x3: two weight sets over the SAME input (k1 + q1) ----------------
__global__ __launch_bounds__(256) void conv3d_kernel(const float* __restrict__ in, const float* __restrict__ wtA,
                                                     const float* __restrict__ wtB,
                                                     float* __restrict__ outA, float* __restrict__ outB){
  int wv = blockIdx.x*4 + (threadIdx.x >> 6);
  int c  = threadIdx.x & 63;
  int p0 = wv << 3;
  int ub = __builtin_amdgcn_readfirstlane(p0);
  int b  = ub >> 14; int i0 = ub & (NPIX-1);
  int y  = i0 >> 7, x0 = i0 & 127;
  float accA[8], accB[8];
  #pragma unroll
  for (int p=0;p<8;++p){ accA[p] = 0.f; accB[p] = 0.f; }
  bool interior = (x0 > 0) && (x0 < 120);
  for (int ky=0; ky<3; ++ky){
    int ny = y + ky - 1;
    if ((unsigned)ny >= 128u) continue;
    const float* rowp = in + (((b<<14) + ny*128) << 6);
    for (int kx=0; kx<3; ++kx){
      const float4* wqA = (const float4*)wtA + (ky*3+kx)*1024 + c;
      const float4* wqB = (const float4*)wtB + (ky*3+kx)*1024 + c;
      #pragma unroll 1
      for (int h=0; h<2; ++h){
        float4 wA[8], wB[8];
        #pragma unroll
        for (int q=0;q<8;++q){ wA[q] = wqA[(h*8+q)*64]; wB[q] = wqB[(h*8+q)*64]; }
        if (interior){
          #pragma unroll
          for (int p=0;p<8;++p){
            const float* ip = rowp + ((x0+p+kx-1)<<6) + h*32;   // shared s_load window
            #pragma unroll
            for (int q=0;q<8;++q){
              float4 iv = *(const float4*)(ip + (q<<2));
              accA[p] = dot4f(iv, wA[q], accA[p]);
              accB[p] = dot4f(iv, wB[q], accB[p]);
            }
          }
        } else {
          #pragma unroll
          for (int p=0;p<8;++p){
            int col = x0 + p + kx - 1;
            if ((unsigned)col < 128u){
              const float* ip = rowp + (col<<6) + h*32;
              #pragma unroll
              for (int q=0;q<8;++q){
                float4 iv = *(const float4*)(ip + (q<<2));
                accA[p] = dot4f(iv, wA[q], accA[p]);
                accB[p] = dot4f(iv, wB[q], accB[p]);
              }
            }
          }
        }
      }
    }
  }
  float* opA = outA + (p0 << 6) + c;
  float* opB = outB + (p0 << 6) + c;
  #pragma unroll
  for (int p=0;p<8;++p){ opA[p*64] = accA[p]; opB[p*64] = accB[p]; }
}

// ---------------- per-channel mean/var accumulation ----------------
__global__ __launch_bounds__(256) void stats_kernel(const float* __restrict__ t, float* __restrict__ stats){
  __shared__ float s1[64], s2[64];
  int tid = threadIdx.x;
  if (tid < 64){ s1[tid] = 0.f; s2[tid] = 0.f; }
  __syncthreads();
  int gid = blockIdx.x*256 + tid;
  float sum = 0.f, ss = 0.f;
  for (int idx = gid; idx < 2097152; idx += 131072){
    float v = t[idx]; sum += v; ss += v*v;
  }
  int c = gid & 63;
  atomicAdd(&s1[c], sum);
  atomicAdd(&s2[c], ss);
  __syncthreads();
  if (tid < 64){ atomicAdd(&stats[tid], s1[tid]); atomicAdd(&stats[64+tid], s2[tid]); }
}

// ---------------- t = relu(a*t + b) (BN+ReLU in place) ----------------
__global__ __launch_bounds__(256) void bnrelu_kernel(float* __restrict__ t, const float* __restrict__ stats,
                                                     const float* __restrict__ g, const float* __restrict__ beta){
  int idx4 = blockIdx.x*256 + threadIdx.x;
  float4 v = ((float4*)t)[idx4];
  int c0 = (idx4 & 15) * 4;
  float a[4], bb[4];
  #pragma unroll
  for (int j=0;j<4;++j){
    int c = c0 + j;
    float mu  = stats[c]    * (1.f/32768.f);
    float var = stats[64+c] * (1.f/32768.f) - mu*mu;
    a[j]  = g[c] * rsqrtf(var + 1e-5f);
    bb[j] = beta[c] - mu*a[j];
  }
  v.x = fmaxf(fmaf(v.x, a[0], bb[0]), 0.f);
  v.y = fmaxf(fmaf(v.y, a[1], bb[1]), 0.f);
  v.z = fmaxf(fmaf(v.z, a[2], bb[2]), 0.f);
  v.w = fmaxf(fmaf(v.w, a[3], bb[3]), 0.f);
  ((float4*)t)[idx4] = v;
}

// ---------------- t = relu(f + a*t + b) (BN + residual + ReLU in place) ----------------
__global__ __launch_bounds__(256) void resfuse_kernel(float* __restrict__ t, const float* __restrict__ f,
                                                      const float* __restrict__ stats, const float* __restrict__ g,
                                                      const float* __restrict__ beta){
  int idx4 = blockIdx.x*256 + threadIdx.x;
  float4 v = ((float4*)t)[idx4];
  float4 fv = ((const float4*)f)[idx4];
  int c0 = (idx4 & 15) * 4;
  float a[4], bb[4];
  #pragma unroll
  for (int j=0;j<4;++j){
    int c = c0 + j;
    float mu  = stats[c]    * (1.f/32768.f);
    float var = stats[64+c] * (1.f/32768.f) - mu*mu;
    a[j]  = g[c] * rsqrtf(var + 1e-5f);
    bb[j] = beta[c] - mu*a[j];
  }
  v.x = fmaxf(fv.x + fmaf(v.x, a[0], bb[0]), 0.f);
  v.y = fmaxf(fv.y + fmaf(v.y, a[1], bb[1]), 0.f);
  v.z = fmaxf(fv.z + fmaf(v.z, a[2], bb[2]), 0.f);
  v.w = fmaxf(fv.w + fmaf(v.w, a[3], bb[3]), 0.f);
  ((float4*)t)[idx4] = v;
}

// ---------------- 1x1 projection + per-pixel L2 norm (wave = 8 px x 64 cout) ----------------
__global__ __launch_bounds__(256) void proj_kernel(const float* __restrict__ r, const float* __restrict__ wt1,
                                                   const float* __restrict__ bias, float* __restrict__ out,
                                                   float* __restrict__ nrm){
  int wv = blockIdx.x*4 + (threadIdx.x >> 6);
  int c  = threadIdx.x & 63;
  int p0 = wv << 3;
  int ub = __builtin_amdgcn_readfirstlane(p0);
  const float4* wq = (const float4*)wt1 + c;
  float4 w[16];
  #pragma unroll
  for (int q=0;q<16;++q) w[q] = wq[q*64];
  float bv = bias ? bias[c] : 0.f;
  #pragma unroll
  for (int p=0;p<8;++p){
    const float* ip = r + ((ub + p) << 6);   // uniform address
    float a0 = bv, a1 = 0.f;
    #pragma unroll
    for (int q=0;q<16;q+=2){
      float4 i0 = *(const float4*)(ip + (q<<2));
      float4 i1 = *(const float4*)(ip + ((q+1)<<2));
      a0 = dot4f(i0, w[q],   a0);
      a1 = dot4f(i1, w[q+1], a1);
    }
    float acc = a0 + a1;
    out[((p0+p)<<6) + c] = acc;
    float s = wred64(acc*acc);
    if (c == 0) nrm[p0+p] = sqrtf(s);
  }
}

// ---------------- edge weights: W[b,i,o] = cos-sim(q_i, k_j) for 5x5 offsets ----------------
#define EW_PAD 68
__global__ __launch_bounds__(256) void edge_kernel(const float* __restrict__ qs, const float* __restrict__ ks,
                                                   const float* __restrict__ nq, const float* __restrict__ nk,
                                                   float* __restrict__ W){
  __shared__ float klds[100*EW_PAD];
  __shared__ float qlds[16*EW_PAD];
  int blk = blockIdx.x;              // 2048 = 2 batches * 128 rows * 8
  int b = blk >> 10; int rem = blk & 1023;
  int y = rem >> 3; int x0 = (rem & 7) << 4;
  int tid = threadIdx.x;
  for (int s = tid; s < 1600; s += 256){
    int cin4 = s & 15; int col = (s >> 4) % 20; int r = (s >> 4) / 20;
    int ry = y - 2 + r; ry = ry < 0 ? 0 : (ry > 127 ? 127 : ry);
    int cx = x0 - 2 + col; cx = cx < 0 ? 0 : (cx > 127 ? 127 : cx);
    float4 v = *(const float4*)(ks + (((b<<14) + ry*128 + cx)<<6) + cin4*4);
    *(float4*)(klds + (r*20+col)*EW_PAD + cin4*4) = v;
  }
  {
    int cin4 = tid & 15; int px = tid >> 4;
    float4 v = *(const float4*)(qs + (((b<<14) + y*128 + x0 + px)<<6) + cin4*4);
    *(float4*)(qlds + px*EW_PAD + cin4*4) = v;
  }
  __syncthreads();
  #pragma unroll
  for (int pair=0; pair<2; ++pair){
    int t2 = tid + pair*256;
    int px = t2 >> 5; int o = t2 & 31;
    if (o < 25){
      int dy = o/5 - 2, dx = o%5 - 2;
      int yy = y + dy, xx = x0 + px + dx;
      bool valid = ((unsigned)yy < 128u) && ((unsigned)xx < 128u);
      const float* kq = klds + ((dy+2)*20 + (px+dx+2))*EW_PAD;
      const float* qq = qlds + px*EW_PAD;
      float a0 = 0.f, a1 = 0.f;
      #pragma unroll
      for (int q=0; q<16; q+=2){
        a0 = dot4f(*(const float4*)(qq + q*4),     *(const float4*)(kq + q*4),     a0);
        a1 = dot4f(*(const float4*)(qq + (q+1)*4), *(const float4*)(kq + (q+1)*4), a1);
      }
      float acc = a0 + a1;
      int gp = (b<<14) + y*128 + x0 + px;
      float wv_ = 0.f;
      if (valid){
        int gj = (b<<14) + yy*128 + xx;
        float rq = 1.f / fmaxf(nq[gp], EPSF);
        float rk = 1.f / fmaxf(nk[gj], EPSF);
        wv_ = acc * rq * rk;
      }
      W[gp*25 + o] = wv_;
    }
  }
}

// ---------------- one message-passing iteration (register sliding window) ----------------
__global__ __launch_bounds__(256) void mp_iter_kernel(const float* __restrict__ src, float* __restrict__ dst,
                                                      const float* __restrict__ W){
  int lane = threadIdx.x & 63;
  int wid  = threadIdx.x >> 6;
  int blk  = blockIdx.x;               // 1024
  int xcd = blk & 7, s = blk >> 3;     // XCD-contiguous rows for L2 locality
  int row_id = xcd*32 + (s >> 2);      // 0..255 (2 batches x 128 rows)
  int q4 = s & 3;
  int b = row_id >> 7, y = row_id & 127;
  int x0 = ((q4 << 2) + wid) << 3;     // 8-pixel group start col
  int gp0 = (b << 14) + y*128 + x0;
  int lo = lane < 25 ? lane : 24;
  float wv[8];
  #pragma unroll
  for (int p=0;p<8;++p) wv[p] = W[(gp0+p)*25 + lo];
  const float* rp[5];
  #pragma unroll
  for (int r=0;r<5;++r){
    int ry = y - 2 + r; ry = ry < 0 ? 0 : (ry > 127 ? 127 : ry);
    rp[r] = src + (((b<<14) + ry*128) << 7) + lane;
  }
  float wa[5][5], wb[5][5];
  #pragma unroll
  for (int cc=0; cc<4; ++cc){
    int xc = x0 - 2 + cc; if (xc < 0) xc = 0;
    int off = xc << 7;
    #pragma unroll
    for (int r=0;r<5;++r){ wa[r][cc] = rp[r][off]; wb[r][cc] = rp[r][off + 64]; }
  }
  #pragma unroll
  for (int p=0;p<8;++p){
    int xl = x0 + p + 2; if (xl > 127) xl = 127;
    int off = xl << 7;
    #pragma unroll
    for (int r=0;r<5;++r){ wa[r][4] = rp[r][off]; wb[r][4] = rp[r][off + 64]; }
    float a0 = 0.f, a1 = 0.f;
    #pragma unroll
    for (int r=0;r<5;++r){
      #pragma unroll
      for (int cc=0;cc<5;++cc){
        float w = rdlane(wv[p], r*5+cc);
        a0 = fmaf(w, wa[r][cc], a0);
        a1 = fmaf(w, wb[r][cc], a1);
      }
    }
    float ss = wred64(a0*a0 + a1*a1);
    float sc = 1.f / fmaxf(sqrtf(ss), EPSF);
    float* dp = dst + ((gp0 + p) << 7) + lane;
    dp[0] = a0*sc; dp[64] = a1*sc;
    #pragma unroll
    for (int r=0;r<5;++r){
      #pragma unroll
      for (int cc=0;cc<4;++cc){ wa[r][cc] = wa[r][cc+1]; wb[r][cc] = wb[r][cc+1]; }
    }
  }
}

// ---------------- normalize agent pixels ----------------
__global__ void mp_agents_kernel(const float* __restrict__ hf, const int* __restrict__ agidx,
                                 float* __restrict__ agbuf){
  int lane = threadIdx.x & 63; int w = threadIdx.x >> 6;  // 16 waves
  int ab = w >> 3, m = w & 7;
  int ai = agidx[m];
  const float* hp = hf + (((ab<<14) + ai) << 7) + lane;
  float v0 = hp[0], v1 = hp[64];
  float ss = wred64(v0*v0 + v1*v1);
  float sc = 1.f / fmaxf(sqrtf(ss), EPSF);
  float* ap = agbuf + (((ab<<3) + m) << 7) + lane;
  ap[0] = v0*sc; ap[64] = v1*sc;
}

// ---------------- final: pix-norm, sim vs agents, softmax, transposed write ----------------
__global__ __launch_bounds__(256) void mp_final_kernel(const float* __restrict__ hf, const float* __restrict__ agbuf,
                                                       float* __restrict__ out){
  int lane = threadIdx.x & 63;
  int wid  = threadIdx.x >> 6;
  int blk  = blockIdx.x;
  int xcd = blk & 7, s = blk >> 3;
  int row_id = xcd*32 + (s >> 2);
  int q4 = s & 3;
  int b = row_id >> 7, y = row_id & 127;
  int x0 = ((q4 << 2) + wid) << 3;
  int gp0 = (b << 14) + y*128 + x0;
  #pragma unroll 1
  for (int p=0;p<8;++p){
    int gp = gp0 + p;
    const float* hp = hf + (gp << 7) + lane;
    float v0 = hp[0], v1 = hp[64];
    float ss = wred64(v0*v0 + v1*v1);
    float sc = 1.f / fmaxf(sqrtf(ss), EPSF);
    float p0 = v0*sc, p1 = v1*sc;
    float sim[8];
    #pragma unroll
    for (int m=0;m<8;++m){
      const float* ap = agbuf + (((b<<3) + m) << 7) + lane;
      sim[m] = wred64(p0*ap[0] + p1*ap[64]);
    }
    float mx = sim[0];
    #pragma unroll
    for (int m=1;m<8;++m) mx = fmaxf(mx, sim[m]);
    float e[8]; float sum = 0.f;
    #pragma unroll
    for (int m=0;m<8;++m){ e[m] = __expf((sim[m]-mx)*10.f); sum += e[m]; }
    float rs = 1.f / sum;
    if (lane < 8){
      float val = e[0];
      #pragma unroll
      for (int m=1;m<8;++m) val = (lane==m) ? e[m] : val;
      out[(((b<<3)+lane)<<14) + y*128 + x0 + p] = val * rs;
    }
  }
}

extern "C" void kernel_launch(void* const* d_in, const int* in_sizes, int n_in,
                              void* d_out, int out_size, void* d_ws, size_t ws_size,
                              hipStream_t stream) {
  (void)in_sizes; (void)n_in; (void)out_size; (void)ws_size;
  const float* x     = (const float*)d_in[0];
  const float* w_bb1 = (const float*)d_in[1];
  const float* b_bb1 = (const float*)d_in[2];
  const float* w_bb2 = (const float*)d_in[3];
  const float* b_bb2 = (const float*)d_in[4];
  const float* w_k1  = (const float*)d_in[5];
  const float* g_k1  = (const float*)d_in[6];
  const float* t_k1  = (const float*)d_in[7];
  const float* w_k2  = (const float*)d_in[8];
  const float* g_k2  = (const float*)d_in[9];
  const float* t_k2  = (const float*)d_in[10];
  const float* w_kp  = (const float*)d_in[11];
  const float* b_kp  = (const float*)d_in[12];
  const float* w_q1  = (const float*)d_in[13];
  const float* g_q1  = (const float*)d_in[14];
  const float* t_q1  = (const float*)d_in[15];
  const float* w_q2  = (const float*)d_in[16];
  const float* g_q2  = (const float*)d_in[17];
  const float* t_q2  = (const float*)d_in[18];
  const float* w_qp  = (const float*)d_in[19];
  const float* h0    = (const float*)d_in[20];
  const int*   agidx = (const int*)d_in[23];
  float* out = (float*)d_out;
  float* ws  = (float*)d_ws;

  // workspace (floats). 6 big 2M-float slots + smalls; HA/HB alias dead slots at MP time.
  float* S0 = ws + 0;          // F1, then T2k
  float* S1 = ws + 2097152;    // F
  float* S2 = ws + 4194304;    // T1k, then T2q
  float* S3 = ws + 6291456;    // T1q, then QS
  float* S4 = ws + 8388608;    // KS
  float* WW = ws + 12582912;   // 819200
  float* NK = ws + 13402112;   // 32768
  float* NQ = ws + 13434880;   // 32768
  float* ST = ws + 13467648;   // 512  (k1:0, k2:128, q1:256, q2:384)
  float* AG = ws + 13468160;   // 2048
  float* WT = ws + 13470208;   // 192512
  float* HA = ws + 0;          // 4194304 floats (S0+S1)
  float* HB = ws + 4194304;    // 4194304 floats (S2+S3)

  prep_kernel<<<755, 256, 0, stream>>>(w_bb2, w_k1, w_k2, w_q1, w_q2, w_kp, w_qp, WT, ST);
  conv1_kernel<<<1024, 256, 0, stream>>>(x, w_bb1, b_bb1, S0);
  conv3s_kernel<<<1024, 256, 0, stream>>>(S0, WT + 0, b_bb2, S1, 1);          // F = S1
  // fused first convs of K and Q branches (shared input window)
  conv3d_kernel<<<1024, 256, 0, stream>>>(S1, WT + 36864, WT + 110592, S2, S3); // T1k=S2, T1q=S3
  stats_kernel<<<512, 256, 0, stream>>>(S2, ST + 0);
  stats_kernel<<<512, 256, 0, stream>>>(S3, ST + 256);
  bnrelu_kernel<<<2048, 256, 0, stream>>>(S2, ST + 0,   g_k1, t_k1);
  bnrelu_kernel<<<2048, 256, 0, stream>>>(S3, ST + 256, g_q1, t_q1);
  // K branch tail
  conv3s_kernel<<<1024, 256, 0, stream>>>(S2, WT + 73728, nullptr, S0, 0);    // T2k = S0
  stats_kernel<<<512, 256, 0, stream>>>(S0, ST + 128);
  resfuse_kernel<<<2048, 256, 0, stream>>>(S0, S1, ST + 128, g_k2, t_k2);
  proj_kernel<<<1024, 256, 0, stream>>>(S0, WT + 184320, b_kp, S4, NK);       // KS = S4
  // Q branch tail
  conv3s_kernel<<<1024, 256, 0, stream>>>(S3, WT + 147456, nullptr, S2, 0);   // T2q = S2
  stats_kernel<<<512, 256, 0, stream>>>(S2, ST + 384);
  resfuse_kernel<<<2048, 256, 0, stream>>>(S2, S1, ST + 384, g_q2, t_q2);
  proj_kernel<<<1024, 256, 0, stream>>>(S2, WT + 188416, nullptr, S3, NQ);    // QS = S3
  // edge weights
  edge_kernel<<<2048, 256, 0, stream>>>(S3, S4, NQ, NK, WW);
  // 32 message-passing iterations (ping-pong)
  const float* sbuf = h0;
  for (int it = 0; it < 32; ++it){
    float* dbuf = (it & 1) ? HB : HA;
    mp_iter_kernel<<<1024, 256, 0, stream>>>(sbuf, dbuf, WW);
    sbuf = dbuf;
  }
  mp_agents_kernel<<<1, 1024, 0, stream>>>(HB, agidx, AG);
  mp_final_kernel<<<1024, 256, 0, stream>>>(HB, AG, out);
}

// Round 5
// 662.399 us; speedup vs baseline: 2.4538x; 1.3605x over previous
//
#include <hip/hip_runtime.h>
#include <math.h>

#define NPIX 16384
#define EPSF 1e-8f

typedef float f32x4 __attribute__((ext_vector_type(4)));
typedef short s16x8 __attribute__((ext_vector_type(8)));

__device__ __forceinline__ float wred64(float s){
  s += __shfl_xor(s, 32); s += __shfl_xor(s, 16); s += __shfl_xor(s, 8);
  s += __shfl_xor(s, 4);  s += __shfl_xor(s, 2);  s += __shfl_xor(s, 1);
  return s;
}
__device__ __forceinline__ float rdlane(float v, int l){
  return __int_as_float(__builtin_amdgcn_readlane(__float_as_int(v), l));
}
__device__ __forceinline__ float dot4f(float4 a, float4 b, float acc){
  acc = fmaf(a.x,b.x,acc); acc = fmaf(a.y,b.y,acc);
  acc = fmaf(a.z,b.z,acc); acc = fmaf(a.w,b.w,acc);
  return acc;
}
// split fp32 into bf16 hi + bf16 lo (RNE both), x ~= hi + lo
__device__ __forceinline__ void bf16split(float v, unsigned short &hi, unsigned short &lo){
  unsigned u = __float_as_uint(v);
  unsigned r = u + 0x7FFFu + ((u >> 16) & 1u);
  hi = (unsigned short)(r >> 16);
  float hf = __uint_as_float(((unsigned)hi) << 16);
  float l = v - hf;
  unsigned u2 = __float_as_uint(l);
  unsigned r2 = u2 + 0x7FFFu + ((u2 >> 16) & 1u);
  lo = (unsigned short)(r2 >> 16);
}

// ---- prep: split conv weights to bf16 hi/lo in MFMA-fragment order; proj weights; zero stats ----
// frag order: idx = (((c*4 + ct)*18 + kb)*64 + lane)*8 + j ; cout = ct*16 + (lane&15),
// k = kb*32 + (lane>>4)*8 + j, source HWIO flat = k*64 + cout  (k = tap*64 + ci)
__global__ __launch_bounds__(256) void prep_kernel(const float* __restrict__ w_bb2, const float* __restrict__ w_k1,
                            const float* __restrict__ w_k2, const float* __restrict__ w_q1,
                            const float* __restrict__ w_q2, const float* __restrict__ w_kp,
                            const float* __restrict__ w_qp, unsigned short* __restrict__ wh,
                            unsigned short* __restrict__ wl, float* __restrict__ wtp,
                            float* __restrict__ stats){
  int gid = blockIdx.x*256 + threadIdx.x;
  if (gid < 184320){
    int j = gid & 7;
    int t1 = gid >> 3;
    int lane = t1 & 63;
    int t2 = t1 >> 6;
    int kb = t2 % 18;
    int t3 = t2 / 18;
    int ct = t3 & 3;
    int c  = t3 >> 2;
    const float* src = c==0? w_bb2 : c==1? w_k1 : c==2? w_k2 : c==3? w_q1 : w_q2;
    int cout = ct*16 + (lane & 15);
    int k = kb*32 + (lane>>4)*8 + j;
    float v = src[k*64 + cout];
    unsigned short h,l; bf16split(v,h,l);
    wh[gid] = h; wl[gid] = l;
  } else if (gid < 192512){
    int t = gid - 184320; int which = t >> 12; int d = t & 4095;
    const float* src = which ? w_qp : w_kp;
    int k = d & 3, cout = (d>>2) & 63, cin4 = d >> 8;
    wtp[t] = src[(cin4*4 + k)*64 + cout];
  } else if (gid < 193024){
    stats[gid - 192512] = 0.f;
  }
}

// ---------------- conv1: 3x3, Cin=3 -> 64 (wave = 8 px x 64 cout) ----------------
__global__ __launch_bounds__(256) void conv1_kernel(const float* __restrict__ x, const float* __restrict__ w,
                                                    const float* __restrict__ bias, float* __restrict__ out){
  int wv = blockIdx.x*4 + (threadIdx.x >> 6);
  int c  = threadIdx.x & 63;
  int p0 = wv << 3;
  int ub = __builtin_amdgcn_readfirstlane(p0);
  int b  = ub >> 14; int i0 = ub & (NPIX-1);
  int y  = i0 >> 7, x0 = i0 & 127;
  float wv_[9][3];
  #pragma unroll
  for (int t=0;t<9;++t)
    #pragma unroll
    for (int ci=0;ci<3;++ci) wv_[t][ci] = w[(t*3+ci)*64 + c];
  float bv = bias[c];
  float acc[8];
  #pragma unroll
  for (int p=0;p<8;++p) acc[p] = bv;
  for (int ky=0; ky<3; ++ky){
    int ny = y + ky - 1;
    if ((unsigned)ny >= 128u) continue;
    const float* rowp = x + ((b<<14) + ny*128)*3;
    for (int kx=0; kx<3; ++kx){
      int t = ky*3 + kx;
      #pragma unroll
      for (int p=0;p<8;++p){
        int col = x0 + p + kx - 1;
        if ((unsigned)col < 128u){
          const float* ip = rowp + col*3;
          acc[p] = fmaf(ip[0], wv_[t][0], acc[p]);
          acc[p] = fmaf(ip[1], wv_[t][1], acc[p]);
          acc[p] = fmaf(ip[2], wv_[t][2], acc[p]);
        }
      }
    }
  }
  float* op = out + (p0 << 6) + c;
  #pragma unroll
  for (int p=0;p<8;++p) op[p*64] = fmaxf(acc[p], 0.f);
}

// ---------------- MFMA conv3x3 64->64 via 3xbf16 split (fp32-grade accuracy) ----------------
// block = 512 thr (8 waves): 64 px (one half-row) x 64 cout. Wave (ch,pxsub): cout 32*ch..+32, px 16*pxsub..+16.
// Input staged (opt BN+ReLU, valid-only) as bf16 hi/lo in XOR-swizzled LDS; weights frag-ordered from prep.
__global__ __launch_bounds__(512) void conv3m_kernel(const float* __restrict__ in,
    const unsigned short* __restrict__ wh, const unsigned short* __restrict__ wl,
    const float* __restrict__ bias, int relu,
    const float* __restrict__ bnst, const float* __restrict__ bng, const float* __restrict__ bnb,
    float* __restrict__ out){
  __shared__ unsigned short lhi[12672];   // [3 rows][66 px][64 ci] bf16, swizzled
  __shared__ unsigned short llo[12672];
  __shared__ float lout[4352];            // [64 px][68 couts] (pad 68 vs bank conflicts)
  __shared__ float la[64], lb[64];
  int blk = blockIdx.x;                   // 512 = b(2) * y(128) * xh(2)
  int xh = blk & 1, y = (blk>>1) & 127, b = blk >> 8;
  int x0 = xh << 6;
  int tid = threadIdx.x;
  if (tid < 64){
    float a = 1.f, bo = 0.f;
    if (bnst){
      float mu  = bnst[tid] * (1.f/32768.f);
      float var = bnst[64+tid] * (1.f/32768.f) - mu*mu;
      a  = bng[tid] * rsqrtf(var + 1e-5f);
      bo = bnb[tid] - mu*a;
    }
    la[tid] = a; lb[tid] = bo;
  }
  __syncthreads();
  // stage: 198 px-rows x 16 float4
  for (int s = tid; s < 3168; s += 512){
    int pr = s >> 4, cq = s & 15;
    int ky = pr / 66, px = pr - ky*66;
    int ny = y + ky - 1, gx = x0 - 1 + px;
    float v0=0.f, v1=0.f, v2=0.f, v3=0.f;
    if ((unsigned)ny < 128u && (unsigned)gx < 128u){
      const float* ip = in + (((b<<14) + ny*128 + gx)<<6) + (cq<<2);
      float4 t = *(const float4*)ip;
      int c0 = cq<<2;
      v0 = fmaxf(fmaf(t.x, la[c0],   lb[c0]),   0.f);   // identity (a=1,b=0) when no BN;
      v1 = fmaxf(fmaf(t.y, la[c0+1], lb[c0+1]), 0.f);   // inputs are already post-ReLU so
      v2 = fmaxf(fmaf(t.z, la[c0+2], lb[c0+2]), 0.f);   // the max() is idempotent
      v3 = fmaxf(fmaf(t.w, la[c0+3], lb[c0+3]), 0.f);
    }
    unsigned short h0,l0,h1,l1,h2,l2,h3,l3;
    bf16split(v0,h0,l0); bf16split(v1,h1,l1); bf16split(v2,h2,l2); bf16split(v3,h3,l3);
    int slot = (cq >> 1) ^ (pr & 7);                    // XOR-swizzle 16B slots within px row
    int byte = pr*128 + (slot<<4) + ((cq & 1) << 3);
    *(uint2*)((char*)lhi + byte) = make_uint2((unsigned)h0 | ((unsigned)h1<<16),
                                              (unsigned)h2 | ((unsigned)h3<<16));
    *(uint2*)((char*)llo + byte) = make_uint2((unsigned)l0 | ((unsigned)l1<<16),
                                              (unsigned)l2 | ((unsigned)l3<<16));
  }
  __syncthreads();
  int lane = tid & 63, wid = tid >> 6;
  int pxsub = wid & 3, ch = wid >> 2;
  int col16 = lane & 15, kgrp = lane >> 4;
  f32x4 acc0 = {0.f,0.f,0.f,0.f}, acc1 = acc0, acl0 = acc0, acl1 = acc0;
  int abase = (ch*2*18)*512 + lane*8;                   // A frag: 512 ushort per (ct,kb)
  #pragma unroll
  for (int kb=0; kb<18; ++kb){
    int tap = kb >> 1;
    int ky = (tap >= 6) ? 2 : (tap >= 3 ? 1 : 0);
    int kx = tap - ky*3;
    int pr = ky*66 + pxsub*16 + col16 + kx;
    int ci0 = ((kb & 1) << 5) + (kgrp << 3);
    int byte = pr*128 + ((((ci0 >> 3) ^ (pr & 7))) << 4);
    s16x8 Bh = *(const s16x8*)((const char*)lhi + byte);
    s16x8 Bl = *(const s16x8*)((const char*)llo + byte);
    int ao = abase + kb*512;
    s16x8 Ah0 = *(const s16x8*)(wh + ao);
    s16x8 Al0 = *(const s16x8*)(wl + ao);
    s16x8 Ah1 = *(const s16x8*)(wh + ao + 9216);
    s16x8 Al1 = *(const s16x8*)(wl + ao + 9216);
    acc0 = __builtin_amdgcn_mfma_f32_16x16x32_bf16(Ah0, Bh, acc0, 0, 0, 0);
    acl0 = __builtin_amdgcn_mfma_f32_16x16x32_bf16(Ah0, Bl, acl0, 0, 0, 0);
    acc1 = __builtin_amdgcn_mfma_f32_16x16x32_bf16(Ah1, Bh, acc1, 0, 0, 0);
    acl1 = __builtin_amdgcn_mfma_f32_16x16x32_bf16(Ah1, Bl, acl1, 0, 0, 0);
    acl0 = __builtin_amdgcn_mfma_f32_16x16x32_bf16(Al0, Bh, acl0, 0, 0, 0);
    acl1 = __builtin_amdgcn_mfma_f32_16x16x32_bf16(Al1, Bh, acl1, 0, 0, 0);
  }
  acc0 = acc0 + acl0;
  acc1 = acc1 + acl1;
  // D frag: col = lane&15 (px), row = (lane>>4)*4 + r (cout-local)
  int pxl = pxsub*16 + col16;
  int co0 = ch*32 + kgrp*4;
  *(f32x4*)(lout + pxl*68 + co0)      = acc0;
  *(f32x4*)(lout + pxl*68 + co0 + 16) = acc1;
  __syncthreads();
  {
    int px = tid >> 3, c8 = (tid & 7) << 3;
    const float* lp = lout + px*68 + c8;
    float r0[8];
    #pragma unroll
    for (int j=0;j<8;++j) r0[j] = lp[j];
    if (bias){
      #pragma unroll
      for (int j=0;j<8;++j) r0[j] += bias[c8+j];
    }
    if (relu){
      #pragma unroll
      for (int j=0;j<8;++j) r0[j] = fmaxf(r0[j], 0.f);
    }
    float* op = out + (((b<<14) + y*128 + x0 + px)<<6) + c8;
    #pragma unroll
    for (int j=0;j<8;++j) op[j] = r0[j];
  }
}

// ---------------- per-channel mean/var accumulation ----------------
__global__ __launch_bounds__(256) void stats_kernel(const float* __restrict__ t, float* __restrict__ stats){
  __shared__ float s1[64], s2[64];
  int tid = threadIdx.x;
  if (tid < 64){ s1[tid] = 0.f; s2[tid] = 0.f; }
  __syncthreads();
  int gid = blockIdx.x*256 + tid;
  float sum = 0.f, ss = 0.f;
  for (int idx = gid; idx < 2097152; idx += 131072){
    float v = t[idx]; sum += v; ss += v*v;
  }
  int c = gid & 63;
  atomicAdd(&s1[c], sum);
  atomicAdd(&s2[c], ss);
  __syncthreads();
  if (tid < 64){ atomicAdd(&stats[tid], s1[tid]); atomicAdd(&stats[64+tid], s2[tid]); }
}

// ---------------- t = relu(f + a*t + b) (BN + residual + ReLU in place) ----------------
__global__ __launch_bounds__(256) void resfuse_kernel(float* __restrict__ t, const float* __restrict__ f,
                                                      const float* __restrict__ stats, const float* __restrict__ g,
                                                      const float* __restrict__ beta){
  int idx4 = blockIdx.x*256 + threadIdx.x;
  float4 v = ((float4*)t)[idx4];
  float4 fv = ((const float4*)f)[idx4];
  int c0 = (idx4 & 15) * 4;
  float a[4], bb[4];
  #pragma unroll
  for (int j=0;j<4;++j){
    int c = c0 + j;
    float mu  = stats[c]    * (1.f/32768.f);
    float var = stats[64+c] * (1.f/32768.f) - mu*mu;
    a[j]  = g[c] * rsqrtf(var + 1e-5f);
    bb[j] = beta[c] - mu*a[j];
  }
  v.x = fmaxf(fv.x + fmaf(v.x, a[0], bb[0]), 0.f);
  v.y = fmaxf(fv.y + fmaf(v.y, a[1], bb[1]), 0.f);
  v.z = fmaxf(fv.z + fmaf(v.z, a[2], bb[2]), 0.f);
  v.w = fmaxf(fv.w + fmaf(v.w, a[3], bb[3]), 0.f);
  ((float4*)t)[idx4] = v;
}

// ---------------- 1x1 projection + per-pixel L2 norm (wave = 8 px x 64 cout) ----------------
__global__ __launch_bounds__(256) void proj_kernel(const float* __restrict__ r, const float* __restrict__ wt1,
                                                   const float* __restrict__ bias, float* __restrict__ out,
                                                   float* __restrict__ nrm){
  int wv = blockIdx.x*4 + (threadIdx.x >> 6);
  int c  = threadIdx.x & 63;
  int p0 = wv << 3;
  int ub = __builtin_amdgcn_readfirstlane(p0);
  const float4* wq = (const float4*)wt1 + c;
  float4 w[16];
  #pragma unroll
  for (int q=0;q<16;++q) w[q] = wq[q*64];
  float bv = bias ? bias[c] : 0.f;
  #pragma unroll
  for (int p=0;p<8;++p){
    const float* ip = r + ((ub + p) << 6);   // uniform address -> s_load
    float a0 = bv, a1 = 0.f;
    #pragma unroll
    for (int q=0;q<16;q+=2){
      float4 i0 = *(const float4*)(ip + (q<<2));
      float4 i1 = *(const float4*)(ip + ((q+1)<<2));
      a0 = dot4f(i0, w[q],   a0);
      a1 = dot4f(i1, w[q+1], a1);
    }
    float acc = a0 + a1;
    out[((p0+p)<<6) + c] = acc;
    float s = wred64(acc*acc);
    if (c == 0) nrm[p0+p] = sqrtf(s);
  }
}

// ---------------- edge weights: W[b,i,o] = cos-sim(q_i, k_j) for 5x5 offsets ----------------
#define EW_PAD 68
__global__ __launch_bounds__(256) void edge_kernel(const float* __restrict__ qs, const float* __restrict__ ks,
                                                   const float* __restrict__ nq, const float* __restrict__ nk,
                                                   float* __restrict__ W){
  __shared__ float klds[100*EW_PAD];
  __shared__ float qlds[16*EW_PAD];
  int blk = blockIdx.x;              // 2048 = 2 batches * 128 rows * 8
  int b = blk >> 10; int rem = blk & 1023;
  int y = rem >> 3; int x0 = (rem & 7) << 4;
  int tid = threadIdx.x;
  for (int s = tid; s < 1600; s += 256){
    int cin4 = s & 15; int col = (s >> 4) % 20; int r = (s >> 4) / 20;
    int ry = y - 2 + r; ry = ry < 0 ? 0 : (ry > 127 ? 127 : ry);
    int cx = x0 - 2 + col; cx = cx < 0 ? 0 : (cx > 127 ? 127 : cx);
    float4 v = *(const float4*)(ks + (((b<<14) + ry*128 + cx)<<6) + cin4*4);
    *(float4*)(klds + (r*20+col)*EW_PAD + cin4*4) = v;
  }
  {
    int cin4 = tid & 15; int px = tid >> 4;
    float4 v = *(const float4*)(qs + (((b<<14) + y*128 + x0 + px)<<6) + cin4*4);
    *(float4*)(qlds + px*EW_PAD + cin4*4) = v;
  }
  __syncthreads();
  #pragma unroll
  for (int pair=0; pair<2; ++pair){
    int t2 = tid + pair*256;
    int px = t2 >> 5; int o = t2 & 31;
    if (o < 25){
      int dy = o/5 - 2, dx = o%5 - 2;
      int yy = y + dy, xx = x0 + px + dx;
      bool valid = ((unsigned)yy < 128u) && ((unsigned)xx < 128u);
      const float* kq = klds + ((dy+2)*20 + (px+dx+2))*EW_PAD;
      const float* qq = qlds + px*EW_PAD;
      float a0 = 0.f, a1 = 0.f;
      #pragma unroll
      for (int q=0; q<16; q+=2){
        a0 = dot4f(*(const float4*)(qq + q*4),     *(const float4*)(kq + q*4),     a0);
        a1 = dot4f(*(const float4*)(qq + (q+1)*4), *(const float4*)(kq + (q+1)*4), a1);
      }
      float acc = a0 + a1;
      int gp = (b<<14) + y*128 + x0 + px;
      float wv_ = 0.f;
      if (valid){
        int gj = (b<<14) + yy*128 + xx;
        float rq = 1.f / fmaxf(nq[gp], EPSF);
        float rk = 1.f / fmaxf(nk[gj], EPSF);
        wv_ = acc * rq * rk;
      }
      W[gp*25 + o] = wv_;
    }
  }
}

// ---------------- one message-passing iteration (register sliding window) ----------------
__global__ __launch_bounds__(256) void mp_iter_kernel(const float* __restrict__ src, float* __restrict__ dst,
                                                      const float* __restrict__ W){
  int lane = threadIdx.x & 63;
  int wid  = threadIdx.x >> 6;
  int blk  = blockIdx.x;               // 1024
  int xcd = blk & 7, s = blk >> 3;     // XCD-contiguous rows for L2 locality
  int row_id = xcd*32 + (s >> 2);      // 0..255 (2 batches x 128 rows)
  int q4 = s & 3;
  int b = row_id >> 7, y = row_id & 127;
  int x0 = ((q4 << 2) + wid) << 3;     // 8-pixel group start col
  int gp0 = (b << 14) + y*128 + x0;
  int lo = lane < 25 ? lane : 24;
  float wv[8];
  #pragma unroll
  for (int p=0;p<8;++p) wv[p] = W[(gp0+p)*25 + lo];
  const float* rp[5];
  #pragma unroll
  for (int r=0;r<5;++r){
    int ry = y - 2 + r; ry = ry < 0 ? 0 : (ry > 127 ? 127 : ry);
    rp[r] = src + (((b<<14) + ry*128) << 7) + lane;
  }
  float wa[5][5], wb[5][5];
  #pragma unroll
  for (int cc=0; cc<4; ++cc){
    int xc = x0 - 2 + cc; if (xc < 0) xc = 0;
    int off = xc << 7;
    #pragma unroll
    for (int r=0;r<5;++r){ wa[r][cc] = rp[r][off]; wb[r][cc] = rp[r][off + 64]; }
  }
  #pragma unroll
  for (int p=0;p<8;++p){
    int xl = x0 + p + 2; if (xl > 127) xl = 127;
    int off = xl << 7;
    #pragma unroll
    for (int r=0;r<5;++r){ wa[r][4] = rp[r][off]; wb[r][4] = rp[r][off + 64]; }
    float a0 = 0.f, a1 = 0.f;
    #pragma unroll
    for (int r=0;r<5;++r){
      #pragma unroll
      for (int cc=0;cc<5;++cc){
        float w = rdlane(wv[p], r*5+cc);
        a0 = fmaf(w, wa[r][cc], a0);
        a1 = fmaf(w, wb[r][cc], a1);
      }
    }
    float ss = wred64(a0*a0 + a1*a1);
    float sc = 1.f / fmaxf(sqrtf(ss), EPSF);
    float* dp = dst + ((gp0 + p) << 7) + lane;
    dp[0] = a0*sc; dp[64] = a1*sc;
    #pragma unroll
    for (int r=0;r<5;++r){
      #pragma unroll
      for (int cc=0;cc<4;++cc){ wa[r][cc] = wa[r][cc+1]; wb[r][cc] = wb[r][cc+1]; }
    }
  }
}

// ---------------- normalize agent pixels ----------------
__global__ void mp_agents_kernel(const float* __restrict__ hf, const int* __restrict__ agidx,
                                 float* __restrict__ agbuf){
  int lane = threadIdx.x & 63; int w = threadIdx.x >> 6;  // 16 waves
  int ab = w >> 3, m = w & 7;
  int ai = agidx[m];
  const float* hp = hf + (((ab<<14) + ai) << 7) + lane;
  float v0 = hp[0], v1 = hp[64];
  float ss = wred64(v0*v0 + v1*v1);
  float sc = 1.f / fmaxf(sqrtf(ss), EPSF);
  float* ap = agbuf + (((ab<<3) + m) << 7) + lane;
  ap[0] = v0*sc; ap[64] = v1*sc;
}

// ---------------- final: pix-norm, sim vs agents, softmax, transposed write ----------------
__global__ __launch_bounds__(256) void mp_final_kernel(const float* __restrict__ hf, const float* __restrict__ agbuf,
                                                       float* __restrict__ out){
  int lane = threadIdx.x & 63;
  int wid  = threadIdx.x >> 6;
  int blk  = blockIdx.x;
  int xcd = blk & 7, s = blk >> 3;
  int row_id = xcd*32 + (s >> 2);
  int q4 = s & 3;
  int b = row_id >> 7, y = row_id & 127;
  int x0 = ((q4 << 2) + wid) << 3;
  int gp0 = (b << 14) + y*128 + x0;
  #pragma unroll 1
  for (int p=0;p<8;++p){
    int gp = gp0 + p;
    const float* hp = hf + (gp << 7) + lane;
    float v0 = hp[0], v1 = hp[64];
    float ss = wred64(v0*v0 + v1*v1);
    float sc = 1.f / fmaxf(sqrtf(ss), EPSF);
    float p0 = v0*sc, p1 = v1*sc;
    float sim[8];
    #pragma unroll
    for (int m=0;m<8;++m){
      const float* ap = agbuf + (((b<<3) + m) << 7) + lane;
      sim[m] = wred64(p0*ap[0] + p1*ap[64]);
    }
    float mx = sim[0];
    #pragma unroll
    for (int m=1;m<8;++m) mx = fmaxf(mx, sim[m]);
    float e[8]; float sum = 0.f;
    #pragma unroll
    for (int m=0;m<8;++m){ e[m] = __expf((sim[m]-mx)*10.f); sum += e[m]; }
    float rs = 1.f / sum;
    if (lane < 8){
      float val = e[0];
      #pragma unroll
      for (int m=1;m<8;++m) val = (lane==m) ? e[m] : val;
      out[(((b<<3)+lane)<<14) + y*128 + x0 + p] = val * rs;
    }
  }
}

extern "C" void kernel_launch(void* const* d_in, const int* in_sizes, int n_in,
                              void* d_out, int out_size, void* d_ws, size_t ws_size,
                              hipStream_t stream) {
  (void)in_sizes; (void)n_in; (void)out_size; (void)ws_size;
  const float* x     = (const float*)d_in[0];
  const float* w_bb1 = (const float*)d_in[1];
  const float* b_bb1 = (const float*)d_in[2];
  const float* w_bb2 = (const float*)d_in[3];
  const float* b_bb2 = (const float*)d_in[4];
  const float* w_k1  = (const float*)d_in[5];
  const float* g_k1  = (const float*)d_in[6];
  const float* t_k1  = (const float*)d_in[7];
  const float* w_k2  = (const float*)d_in[8];
  const float* g_k2  = (const float*)d_in[9];
  const float* t_k2  = (const float*)d_in[10];
  const float* w_kp  = (const float*)d_in[11];
  const float* b_kp  = (const float*)d_in[12];
  const float* w_q1  = (const float*)d_in[13];
  const float* g_q1  = (const float*)d_in[14];
  const float* t_q1  = (const float*)d_in[15];
  const float* w_q2  = (const float*)d_in[16];
  const float* g_q2  = (const float*)d_in[17];
  const float* t_q2  = (const float*)d_in[18];
  const float* w_qp  = (const float*)d_in[19];
  const float* h0    = (const float*)d_in[20];
  const int*   agidx = (const int*)d_in[23];
  float* out = (float*)d_out;
  float* ws  = (float*)d_ws;

  // workspace (floats). 5 big 2M-float slots + smalls; HA/HB alias dead slots at MP time.
  float* S0 = ws + 0;          // F1, then T2k
  float* S1 = ws + 2097152;    // F
  float* S2 = ws + 4194304;    // T1k, then T2q
  float* S3 = ws + 6291456;    // T1q, then QS
  float* S4 = ws + 8388608;    // KS
  float* WW = ws + 12582912;   // 819200
  float* NK = ws + 13402112;   // 32768
  float* NQ = ws + 13434880;   // 32768
  float* ST = ws + 13467648;   // 512  (k1:0, k2:128, q1:256, q2:384)
  float* AG = ws + 13468160;   // 2048
  float* WTp = ws + 13470208;  // 8192 (proj: kp@0, qp@4096)
  unsigned short* WH = (unsigned short*)(ws + 13478400);  // 184320 ushort (5 convs x 36864)
  unsigned short* WL = WH + 184320;
  float* HA = ws + 0;          // 4194304 floats (S0+S1)
  float* HB = ws + 4194304;    // 4194304 floats (S2+S3)

  prep_kernel<<<754, 256, 0, stream>>>(w_bb2, w_k1, w_k2, w_q1, w_q2, w_kp, w_qp, WH, WL, WTp, ST);
  conv1_kernel<<<1024, 256, 0, stream>>>(x, w_bb1, b_bb1, S0);
  // bb2: bias + relu epilogue
  conv3m_kernel<<<512, 512, 0, stream>>>(S0, WH + 0, WL + 0, b_bb2, 1, nullptr, nullptr, nullptr, S1);
  // k1 / q1: raw outputs (stats after)
  conv3m_kernel<<<512, 512, 0, stream>>>(S1, WH + 36864, WL + 36864, nullptr, 0, nullptr, nullptr, nullptr, S2);
  stats_kernel<<<512, 256, 0, stream>>>(S2, ST + 0);
  conv3m_kernel<<<512, 512, 0, stream>>>(S1, WH + 3*36864, WL + 3*36864, nullptr, 0, nullptr, nullptr, nullptr, S3);
  stats_kernel<<<512, 256, 0, stream>>>(S3, ST + 256);
  // k2: BN(k1 stats)+ReLU folded into staging
  conv3m_kernel<<<512, 512, 0, stream>>>(S2, WH + 2*36864, WL + 2*36864, nullptr, 0, ST + 0, g_k1, t_k1, S0);
  stats_kernel<<<512, 256, 0, stream>>>(S0, ST + 128);
  resfuse_kernel<<<2048, 256, 0, stream>>>(S0, S1, ST + 128, g_k2, t_k2);
  proj_kernel<<<1024, 256, 0, stream>>>(S0, WTp + 0, b_kp, S4, NK);           // KS = S4
  // q2
  conv3m_kernel<<<512, 512, 0, stream>>>(S3, WH + 4*36864, WL + 4*36864, nullptr, 0, ST + 256, g_q1, t_q1, S2);
  stats_kernel<<<512, 256, 0, stream>>>(S2, ST + 384);
  resfuse_kernel<<<2048, 256, 0, stream>>>(S2, S1, ST + 384, g_q2, t_q2);
  proj_kernel<<<1024, 256, 0, stream>>>(S2, WTp + 4096, nullptr, S3, NQ);     // QS = S3
  // edge weights
  edge_kernel<<<2048, 256, 0, stream>>>(S3, S4, NQ, NK, WW);
  // 32 message-passing iterations (ping-pong)
  const float* sbuf = h0;
  for (int it = 0; it < 32; ++it){
    float* dbuf = (it & 1) ? HB : HA;
    mp_iter_kernel<<<1024, 256, 0, stream>>>(sbuf, dbuf, WW);
    sbuf = dbuf;
  }
  mp_agents_kernel<<<1, 1024, 0, stream>>>(HB, agidx, AG);
  mp_final_kernel<<<1024, 256, 0, stream>>>(HB, AG, out);
}